// Round 7
// baseline (207.331 us; speedup 1.0000x reference)
//
#include <hip/hip_runtime.h>

#define NEAR0f 1e-8f
#define REGf   0.002f
#define NBLK   1024
#define NTHR   256

typedef float __attribute__((ext_vector_type(4))) f32x4;
typedef int   __attribute__((ext_vector_type(4))) i32x4;

__device__ __forceinline__ f32x4 ntload(const f32x4* p) { return __builtin_nontemporal_load(p); }
__device__ __forceinline__ i32x4 ntload(const i32x4* p) { return __builtin_nontemporal_load(p); }

__device__ __forceinline__ float wave_reduce(float v) {
#pragma unroll
    for (int off = 32; off > 0; off >>= 1)
        v += __shfl_down(v, off, 64);
    return v;
}

// sum of log(selected prob) over 4 elements — ONE log via product
// (prod in [1e-32, 1], safely above fp32 min-normal 1.2e-38)
__device__ __forceinline__ float nll4(f32x4 p, i32x4 l) {
    float a0 = fmaxf(l.x ? p.x : 1.0f - p.x, NEAR0f);
    float a1 = fmaxf(l.y ? p.y : 1.0f - p.y, NEAR0f);
    float a2 = fmaxf(l.z ? p.z : 1.0f - p.z, NEAR0f);
    float a3 = fmaxf(l.w ? p.w : 1.0f - p.w, NEAR0f);
    return __logf((a0 * a1) * (a2 * a3));
}

__device__ __forceinline__ float sq4(f32x4 a, float acc) {
    return fmaf(a.x, a.x, fmaf(a.y, a.y, fmaf(a.z, a.z, fmaf(a.w, a.w, acc))));
}

// ws layout: [0] ticket (u32, memset to 0 by host each call); [16..] partials.
// Single fused kernel: per-block partials -> ticket -> last block finalizes.
__global__ __launch_bounds__(NTHR, 2) void reduce_all(
    const f32x4* __restrict__ p4,
    const i32x4* __restrict__ l4,
    const f32x4* __restrict__ w1,
    const f32x4* __restrict__ w2,
    unsigned* __restrict__ ticket,
    float* __restrict__ partials,
    float* __restrict__ out,
    int n4, int w4, float invN)
{
    const int tid    = blockIdx.x * blockDim.x + threadIdx.x;
    const int stride = gridDim.x * blockDim.x;

    float na[8] = {0, 0, 0, 0, 0, 0, 0, 0};
    int i = tid;
    for (; i + 7 * stride < n4; i += 8 * stride) {
        f32x4 p[8];
        i32x4 l[8];
#pragma unroll
        for (int u = 0; u < 8; ++u) p[u] = ntload(p4 + i + u * stride);
#pragma unroll
        for (int u = 0; u < 8; ++u) l[u] = ntload(l4 + i + u * stride);
#pragma unroll
        for (int u = 0; u < 8; ++u) na[u] -= nll4(p[u], l[u]);
    }
    for (; i < n4; i += stride) {
        na[0] -= nll4(ntload(p4 + i), ntload(l4 + i));
    }
    float nll = ((na[0] + na[1]) + (na[2] + na[3]))
              + ((na[4] + na[5]) + (na[6] + na[7]));

    float s1v[4] = {0, 0, 0, 0}, s2v[4] = {0, 0, 0, 0};
    int j = tid;
    for (; j + 3 * stride < w4; j += 4 * stride) {
        f32x4 a[4], b[4];
#pragma unroll
        for (int u = 0; u < 4; ++u) a[u] = ntload(w1 + j + u * stride);
#pragma unroll
        for (int u = 0; u < 4; ++u) b[u] = ntload(w2 + j + u * stride);
#pragma unroll
        for (int u = 0; u < 4; ++u) {
            s1v[u] = sq4(a[u], s1v[u]);
            s2v[u] = sq4(b[u], s2v[u]);
        }
    }
    for (; j < w4; j += stride) {
        s1v[0] = sq4(ntload(w1 + j), s1v[0]);
        s2v[0] = sq4(ntload(w2 + j), s2v[0]);
    }
    float s1 = (s1v[0] + s1v[1]) + (s1v[2] + s1v[3]);
    float s2 = (s2v[0] + s2v[1]) + (s2v[2] + s2v[3]);

    nll = wave_reduce(nll);
    s1  = wave_reduce(s1);
    s2  = wave_reduce(s2);

    __shared__ float sm[3][4];
    const int lane = threadIdx.x & 63;
    const int wave = threadIdx.x >> 6;
    if (lane == 0) { sm[0][wave] = nll; sm[1][wave] = s1; sm[2][wave] = s2; }
    __syncthreads();

    __shared__ int is_last;
    if (threadIdx.x == 0) {
        partials[blockIdx.x * 3 + 0] = sm[0][0] + sm[0][1] + sm[0][2] + sm[0][3];
        partials[blockIdx.x * 3 + 1] = sm[1][0] + sm[1][1] + sm[1][2] + sm[1][3];
        partials[blockIdx.x * 3 + 2] = sm[2][0] + sm[2][1] + sm[2][2] + sm[2][3];
        __threadfence();   // flush partials to device coherence point (cross-XCD)
        is_last = (atomicAdd(ticket, 1u) == (unsigned)gridDim.x - 1u);
    }
    __syncthreads();

    if (is_last) {
        float tn = 0.0f, t1 = 0.0f, t2 = 0.0f;
        // agent-scope atomic loads: bypass this XCD's (possibly stale) caches
        for (int b = threadIdx.x; b < gridDim.x; b += blockDim.x) {
            tn += __hip_atomic_load(&partials[b * 3 + 0], __ATOMIC_RELAXED, __HIP_MEMORY_SCOPE_AGENT);
            t1 += __hip_atomic_load(&partials[b * 3 + 1], __ATOMIC_RELAXED, __HIP_MEMORY_SCOPE_AGENT);
            t2 += __hip_atomic_load(&partials[b * 3 + 2], __ATOMIC_RELAXED, __HIP_MEMORY_SCOPE_AGENT);
        }
        tn = wave_reduce(tn);
        t1 = wave_reduce(t1);
        t2 = wave_reduce(t2);
        if (lane == 0) { sm[0][wave] = tn; sm[1][wave] = t1; sm[2][wave] = t2; }
        __syncthreads();
        if (threadIdx.x == 0) {
            float fn = sm[0][0] + sm[0][1] + sm[0][2] + sm[0][3];
            float f1 = sm[1][0] + sm[1][1] + sm[1][2] + sm[1][3];
            float f2 = sm[2][0] + sm[2][1] + sm[2][2] + sm[2][3];
            out[0] = fn * invN + REGf * (sqrtf(f1) + sqrtf(f2));
        }
    }
}

extern "C" void kernel_launch(void* const* d_in, const int* in_sizes, int n_in,
                              void* d_out, int out_size, void* d_ws, size_t ws_size,
                              hipStream_t stream) {
    const float* out1  = (const float*)d_in[0];   // [N,1] fp32
    const int*   label = (const int*)d_in[1];     // [N] int32
    const float* W1    = (const float*)d_in[2];   // [1024,4096] fp32
    const float* W2    = (const float*)d_in[3];   // [4096,1024] fp32

    const int N  = in_sizes[0];
    const int n4 = N / 4;
    const int w4 = in_sizes[2] / 4;               // W1 and W2 same size

    unsigned* ticket   = (unsigned*)d_ws;
    float*    partials = (float*)((char*)d_ws + 16);

    hipMemsetAsync(d_ws, 0, 4, stream);           // zero the ticket (graph-legal)
    reduce_all<<<NBLK, NTHR, 0, stream>>>(
        (const f32x4*)out1, (const i32x4*)label,
        (const f32x4*)W1,   (const f32x4*)W2,
        ticket, partials, (float*)d_out,
        n4, w4, 1.0f / (float)N);
}